// Round 7
// baseline (87.977 us; speedup 1.0000x reference)
//
#include <hip/hip_runtime.h>
#include <cstdint>

#define NRC 4          // real channels
#define NCC 6          // complex channels
#define HD 64
#define CW 16          // z/out row width (floats)

typedef _Float16 half8  __attribute__((ext_vector_type(8)));
typedef _Float16 half2v __attribute__((ext_vector_type(2)));
typedef float    f32x4  __attribute__((ext_vector_type(4)));

// Block-invariant pre-packed weights (rewritten every call by prep_kernel).
__device__ uint32_t WMPK[40960];   // [ch 10][l 2][frag 512] x half8 (4 u32): hidden-layer A-frags
__device__ uint32_t WLPK[5120];    // [ch 10][frag 128] x half8: final-layer A-frags
__device__ uint32_t W0PKD[320];    // [ch 10][32] packed f16 pairs of W0
__device__ uint32_t B0PKD[320];    // [ch 10][32] packed f16 pairs of b0

__device__ __forceinline__ uint32_t pkh(float a, float b) {
    auto h = __builtin_amdgcn_cvt_pkrtz(a, b);   // __fp16 ext_vector(2), 4 bytes
    return __builtin_bit_cast(uint32_t, h);
}
__device__ __forceinline__ half2v u2h(uint32_t u) { return __builtin_bit_cast(half2v, u); }
__device__ __forceinline__ uint32_t h2u(half2v h) { return __builtin_bit_cast(uint32_t, h); }

__device__ __forceinline__ half2v hmax0(half2v h) {
#if __has_builtin(__builtin_elementwise_max)
    half2v z = {};
    return __builtin_elementwise_max(h, z);      // v_pk_max_f16
#else
    half2v r;
    r[0] = h[0] > (_Float16)0 ? h[0] : (_Float16)0;
    r[1] = h[1] > (_Float16)0 ? h[1] : (_Float16)0;
    return r;
#endif
}
__device__ __forceinline__ half2v hfma(half2v a, half2v b, half2v c) {
#if __has_builtin(__builtin_elementwise_fma)
    return __builtin_elementwise_fma(a, b, c);   // v_pk_fma_f16
#else
    return a * b + c;
#endif
}

// ---------------------------------------------------------------------------
// prep: pack weights into MFMA-fragment order (runs once per call)
// WMPK frag = ((kt*4+g)*16 + l15)*4 + m ; element e <-> k=(kt*4+g)*8+e, n=m*16+l15
// ---------------------------------------------------------------------------
__global__ void prep_kernel(const float* __restrict__ Wm_r, const float* __restrict__ Wm_c,
                            const float* __restrict__ Wl_r, const float* __restrict__ Wl_c,
                            const float* __restrict__ W0_r, const float* __restrict__ W0_c,
                            const float* __restrict__ b0_r, const float* __restrict__ b0_c)
{
    const int gid = blockIdx.x * 256 + threadIdx.x;
    if (gid < 10240) {                          // hidden-layer fragments
        const int ch = gid >> 10, rem = gid & 1023;
        const int l = rem >> 9, frag = rem & 511;
        const int m = frag & 3, rowsel = frag >> 2;
        const int l15 = rowsel & 15, kg = rowsel >> 4;   // kg = kt*4+g
        const int n = m * 16 + l15;
        const float* W = (ch < NRC) ? (Wm_r + (l * NRC + ch) * HD * HD)
                                    : (Wm_c + (l * NCC + (ch - NRC)) * HD * HD);
        const float* s = W + (kg * 8) * HD + n;          // W[k][n], stride HD per k
        uint4 q = { pkh(s[0],      s[HD]),
                    pkh(s[2*HD],   s[3*HD]),
                    pkh(s[4*HD],   s[5*HD]),
                    pkh(s[6*HD],   s[7*HD]) };
        *(uint4*)&WMPK[gid * 4] = q;
    } else if (gid < 11520) {                   // final-layer fragments
        const int idx = gid - 10240;
        const int ch = idx >> 7, frag = idx & 127;
        const int l15 = frag & 15, kg = frag >> 4;
        const int No = (ch < NRC) ? 1 : 2;
        const float* Wl = (ch < NRC) ? (Wl_r + ch * HD) : (Wl_c + (ch - NRC) * HD * 2);
        float v[8];
        #pragma unroll
        for (int e = 0; e < 8; ++e)
            v[e] = (l15 < No) ? Wl[(kg * 8 + e) * No + l15] : 0.f;
        uint4 q = { pkh(v[0], v[1]), pkh(v[2], v[3]), pkh(v[4], v[5]), pkh(v[6], v[7]) };
        *(uint4*)&WLPK[idx * 4] = q;
    } else if (gid < 12160) {                   // W0 / b0 packed pairs
        const int idx = gid - 11520;
        const int which = idx / 320, r = idx % 320;
        const int ch = r >> 5, j = r & 31;
        const float* src;
        if (which == 0) src = (ch < NRC) ? (W0_r + ch * HD) : (W0_c + (ch - NRC) * HD);
        else            src = (ch < NRC) ? (b0_r + ch * HD) : (b0_c + (ch - NRC) * HD);
        const uint32_t v = pkh(src[2 * j], src[2 * j + 1]);
        if (which == 0) W0PKD[r] = v; else B0PKD[r] = v;
    }
}

// ---------------------------------------------------------------------------
// main: block = 5 waves x 64 tokens; wave wv handles channels wv and wv+5.
// All 10 channels of a token tile live in ONE block -> full-line z reads and
// out writes (no cross-block partial-line churn). No __syncthreads anywhere.
// LDS = 5 waves x 2048 words = 40960 B -> 4 blocks/CU (20 waves/CU).
// ---------------------------------------------------------------------------
__global__ __launch_bounds__(320, 5) void koop_kernel(
    const float* __restrict__ z,
    const float* __restrict__ bm_r, const float* __restrict__ bl_r,
    const float* __restrict__ bm_c, const float* __restrict__ bl_c,
    float* __restrict__ out)
{
    __shared__ uint32_t smem[10240];

    const int tid  = threadIdx.x;
    const int lane = tid & 63;
    const int wv   = tid >> 6;        // 0..4
    const int t    = blockIdx.x * 64 + lane;

    const int l15 = lane & 15;
    const int g   = lane >> 4;
    const int hbase = wv * 2048;
    float* smf = (float*)smem;
    const int obase = hbase;          // route words [hbase, hbase+128): 64 tok x 2 f32

    #pragma unroll
    for (int ci = 0; ci < 2; ++ci) {
        const int ch = ci * 5 + wv;   // wave wv: channels wv, wv+5
        const bool isReal = (ch < NRC);
        const int  pc     = ch - NRC;

        // ---------------- per-lane token input ----------------
        float xin = 0.f, z1 = 0.f, z2 = 0.f, sval;
        if (isReal) {
            xin = z[t * CW + ch];
            sval = xin;
        } else {
            float2 zz = *(const float2*)(z + t * CW + NRC + 2 * pc);
            z1 = zz.x; z2 = zz.y;
            sval = z1 * z1 + z2 * z2;
        }

        // ---------------- A-fragments from pre-packed global (L2-hit) ----------------
        const uint32_t* wm1 = &WMPK[(ch * 2 + 0) * 2048];
        const uint32_t* wm2 = &WMPK[(ch * 2 + 1) * 2048];
        half8 A1[4][2];
        #pragma unroll
        for (int m = 0; m < 4; ++m)
            #pragma unroll
            for (int kt = 0; kt < 2; ++kt)
                A1[m][kt] = *(const half8*)&wm1[((((kt * 4 + g) * 16 + l15) * 4) + m) * 4];

        half8 Af[2];
        #pragma unroll
        for (int kt = 0; kt < 2; ++kt)
            Af[kt] = *(const half8*)&WLPK[(ch * 128 + (kt * 4 + g) * 16 + l15) * 4];

        // ---------------- stage 1: h0 = relu(s*W0 + b0), packed f16, lane = token ----------------
        {
            const half2v sv = u2h(pkh(sval, sval));
            const uint32_t* w0p = &W0PKD[ch * 32];
            const uint32_t* b0p = &B0PKD[ch * 32];
            #pragma unroll
            for (int blk = 0; blk < 8; ++blk) {
                uint32_t q[4];
                #pragma unroll
                for (int j = 0; j < 4; ++j) {
                    half2v h = hfma(sv, u2h(w0p[blk * 4 + j]), u2h(b0p[blk * 4 + j]));
                    q[j] = h2u(hmax0(h));
                }
                const int woff = hbase + lane * 32 + (((blk + lane) & 7) << 2);
                uint4 qq = { q[0], q[1], q[2], q[3] };
                *(uint4*)&smem[woff] = qq;
            }
        }

        // ---------------- two hidden layers via MFMA ----------------
        // D[nH][tok]; D col = token (lane&15), D row = nH = 16*m + 4*g + reg.
        for (int l = 0; l < 2; ++l) {
            half8 A[4][2];
            if (l == 0) {
                #pragma unroll
                for (int m = 0; m < 4; ++m)
                    #pragma unroll
                    for (int kt = 0; kt < 2; ++kt)
                        A[m][kt] = A1[m][kt];
            } else {
                #pragma unroll
                for (int m = 0; m < 4; ++m)
                    #pragma unroll
                    for (int kt = 0; kt < 2; ++kt)
                        A[m][kt] = *(const half8*)&wm2[((((kt * 4 + g) * 16 + l15) * 4) + m) * 4];
            }
            const float* bm = isReal ? (bm_r + (l * NRC + ch) * HD)
                                     : (bm_c + (l * NCC + pc) * HD);
            f32x4 bv[4];
            #pragma unroll
            for (int m = 0; m < 4; ++m)
                bv[m] = *(const f32x4*)(bm + m * 16 + g * 4);

            #pragma unroll
            for (int th = 0; th < 2; ++th) {
                f32x4 acc[4][2];
                #pragma unroll
                for (int m = 0; m < 4; ++m)
                    #pragma unroll
                    for (int u = 0; u < 2; ++u)
                        acc[m][u] = bv[m];                // bias folded into C

                #pragma unroll
                for (int u = 0; u < 2; ++u) {
                    const int tt = th * 2 + u;
                    #pragma unroll
                    for (int kt = 0; kt < 2; ++kt) {
                        const int row = tt * 16 + l15;
                        const int blk = kt * 4 + g;
                        half8 Bf = *(const half8*)&smem[hbase + row * 32 + (((blk + row) & 7) << 2)];
                        #pragma unroll
                        for (int m = 0; m < 4; ++m)
                            acc[m][u] = __builtin_amdgcn_mfma_f32_16x16x32_f16(A[m][kt], Bf, acc[m][u], 0, 0, 0);
                    }
                }

                // epilogue: pack f16 + packed relu + write back (half-disjoint rows)
                #pragma unroll
                for (int u = 0; u < 2; ++u) {
                    const int tt = th * 2 + u;
                    const int row = tt * 16 + l15;
                    #pragma unroll
                    for (int m = 0; m < 4; ++m) {
                        f32x4 v = acc[m][u];
                        uint32_t p0 = h2u(hmax0(u2h(pkh(v[0], v[1]))));
                        uint32_t p1 = h2u(hmax0(u2h(pkh(v[2], v[3]))));
                        const int blk  = 2 * m + (g >> 1);
                        const int woff = hbase + row * 32 + (((blk + row) & 7) << 2) + (g & 1) * 2;
                        uint2 q = { p0, p1 };
                        *(uint2*)&smem[woff] = q;
                    }
                }
            }
        }

        // ---------------- final layer: out_raw[o][tok] via MFMA (bias in C-init) ----------------
        const float* bl = isReal ? (bl_r + ch) : (bl_c + pc * 2);
        f32x4 cf0 = (f32x4){0.f, 0.f, 0.f, 0.f};
        if (g == 0) { cf0[0] = bl[0]; if (!isReal) cf0[1] = bl[1]; }
        f32x4 accf[4];
        #pragma unroll
        for (int tt = 0; tt < 4; ++tt) accf[tt] = cf0;
        #pragma unroll
        for (int tt = 0; tt < 4; ++tt) {
            #pragma unroll
            for (int kt = 0; kt < 2; ++kt) {
                const int row = tt * 16 + l15;
                const int blk = kt * 4 + g;
                half8 Bf = *(const half8*)&smem[hbase + row * 32 + (((blk + row) & 7) << 2)];
                accf[tt] = __builtin_amdgcn_mfma_f32_16x16x32_f16(Af[kt], Bf, accf[tt], 0, 0, 0);
            }
        }

        // ---------------- route results to lane = token (wave-local, reuse own h words) ----------------
        if (g == 0) {
            #pragma unroll
            for (int tt = 0; tt < 4; ++tt) {
                const int tok = tt * 16 + l15;
                if (isReal) {
                    smf[obase + tok * 2] = accf[tt][0];
                } else {
                    float2 mo = { accf[tt][0], accf[tt][1] };
                    *(float2*)&smf[obase + tok * 2] = mo;
                }
            }
        }
        __asm__ volatile("s_waitcnt lgkmcnt(0)" ::: "memory");
        __builtin_amdgcn_sched_barrier(0);

        if (isReal) {
            float lam = smf[obase + lane * 2];
            out[t * CW + ch] = xin * lam;
        } else {
            float2 mo = *(const float2*)&smf[obase + lane * 2];
            float ex = __expf(mo.x);
            float mc = ex * __cosf(mo.y);
            float ms = ex * __sinf(mo.y);
            float o1 =  z1 * mc + z2 * ms;
            float o2 =  z2 * mc - z1 * ms;
            *(float2*)(out + t * CW + NRC + 2 * pc) = make_float2(o1, o2);
        }
        // ensure route reads of this channel complete before next channel's stage-1 overwrites
        __asm__ volatile("s_waitcnt lgkmcnt(0)" ::: "memory");
        __builtin_amdgcn_sched_barrier(0);
    }
}

extern "C" void kernel_launch(void* const* d_in, const int* in_sizes, int n_in,
                              void* d_out, int out_size, void* d_ws, size_t ws_size,
                              hipStream_t stream) {
    (void)in_sizes; (void)n_in; (void)d_ws; (void)ws_size; (void)out_size;
    const float* z    = (const float*)d_in[0];
    const float* W0_r = (const float*)d_in[1];
    const float* b0_r = (const float*)d_in[2];
    const float* Wm_r = (const float*)d_in[3];
    const float* bm_r = (const float*)d_in[4];
    const float* Wl_r = (const float*)d_in[5];
    const float* bl_r = (const float*)d_in[6];
    const float* W0_c = (const float*)d_in[7];
    const float* b0_c = (const float*)d_in[8];
    const float* Wm_c = (const float*)d_in[9];
    const float* bm_c = (const float*)d_in[10];
    const float* Wl_c = (const float*)d_in[11];
    const float* bl_c = (const float*)d_in[12];
    float* outp = (float*)d_out;

    prep_kernel<<<48, 256, 0, stream>>>(Wm_r, Wm_c, Wl_r, Wl_c, W0_r, W0_c, b0_r, b0_c);
    koop_kernel<<<1024, 320, 0, stream>>>(z, bm_r, bl_r, bm_c, bl_c, outp);
}

// Round 8
// 44.086 us; speedup vs baseline: 1.9956x; 1.9956x over previous
//
#include <hip/hip_runtime.h>
#include <cstdint>

#define NRC 4          // real channels
#define NCC 6          // complex channels
#define HD 64
#define CW 16          // z/out row width (floats)

typedef _Float16 half8  __attribute__((ext_vector_type(8)));
typedef _Float16 half2v __attribute__((ext_vector_type(2)));
typedef float    f32x4  __attribute__((ext_vector_type(4)));

// Block-invariant pre-packed weights (rewritten every call by prep_kernel).
// WMPK frag id f = kt*256 + m*64 + lane  -> lane-contiguous 16B = coalesced loads.
__device__ uint32_t WMPK[40960];   // [ch 10][l 2][frag 512] x half8 (4 u32)
__device__ uint32_t WLPK[5120];    // [ch 10][frag 128 = kt*64+lane] x half8
__device__ uint32_t W0PKD[320];    // [ch 10][32] packed f16 pairs of W0
__device__ uint32_t B0PKD[320];    // [ch 10][32] packed f16 pairs of b0

__device__ __forceinline__ uint32_t pkh(float a, float b) {
    auto h = __builtin_amdgcn_cvt_pkrtz(a, b);   // __fp16 ext_vector(2), 4 bytes
    return __builtin_bit_cast(uint32_t, h);
}
__device__ __forceinline__ half2v u2h(uint32_t u) { return __builtin_bit_cast(half2v, u); }
__device__ __forceinline__ uint32_t h2u(half2v h) { return __builtin_bit_cast(uint32_t, h); }

__device__ __forceinline__ half2v hmax0(half2v h) {
#if __has_builtin(__builtin_elementwise_max)
    half2v z = {};
    return __builtin_elementwise_max(h, z);      // v_pk_max_f16
#else
    half2v r;
    r[0] = h[0] > (_Float16)0 ? h[0] : (_Float16)0;
    r[1] = h[1] > (_Float16)0 ? h[1] : (_Float16)0;
    return r;
#endif
}
__device__ __forceinline__ half2v hfma(half2v a, half2v b, half2v c) {
#if __has_builtin(__builtin_elementwise_fma)
    return __builtin_elementwise_fma(a, b, c);   // v_pk_fma_f16
#else
    return a * b + c;
#endif
}

// ---------------------------------------------------------------------------
// prep: pack weights into MFMA-fragment order, lane-coalesced
// ---------------------------------------------------------------------------
__global__ void prep_kernel(const float* __restrict__ Wm_r, const float* __restrict__ Wm_c,
                            const float* __restrict__ Wl_r, const float* __restrict__ Wl_c,
                            const float* __restrict__ W0_r, const float* __restrict__ W0_c,
                            const float* __restrict__ b0_r, const float* __restrict__ b0_c)
{
    const int gid = blockIdx.x * 256 + threadIdx.x;
    if (gid < 10240) {                          // hidden-layer fragments
        const int ch = gid >> 10, rem = gid & 1023;
        const int l = rem >> 9, f = rem & 511;
        const int kt = f >> 8, m = (f >> 6) & 3, lane = f & 63;
        const int g = (lane >> 4) & 3, l15 = lane & 15;
        const int n = m * 16 + l15;
        const int k0 = (kt * 4 + g) * 8;
        const float* W = (ch < NRC) ? (Wm_r + (l * NRC + ch) * HD * HD)
                                    : (Wm_c + (l * NCC + (ch - NRC)) * HD * HD);
        const float* s = W + k0 * HD + n;                // W[k][n], stride HD per k
        uint4 q = { pkh(s[0],      s[HD]),
                    pkh(s[2*HD],   s[3*HD]),
                    pkh(s[4*HD],   s[5*HD]),
                    pkh(s[6*HD],   s[7*HD]) };
        *(uint4*)&WMPK[gid * 4] = q;
    } else if (gid < 11520) {                   // final-layer fragments
        const int idx = gid - 10240;
        const int ch = idx >> 7, f = idx & 127;
        const int kt = f >> 6, lane = f & 63;
        const int g = (lane >> 4) & 3, l15 = lane & 15;
        const int No = (ch < NRC) ? 1 : 2;
        const float* Wl = (ch < NRC) ? (Wl_r + ch * HD) : (Wl_c + (ch - NRC) * HD * 2);
        float v[8];
        #pragma unroll
        for (int e = 0; e < 8; ++e)
            v[e] = (l15 < No) ? Wl[((kt * 4 + g) * 8 + e) * No + l15] : 0.f;
        uint4 q = { pkh(v[0], v[1]), pkh(v[2], v[3]), pkh(v[4], v[5]), pkh(v[6], v[7]) };
        *(uint4*)&WLPK[idx * 4] = q;
    } else if (gid < 12160) {                   // W0 / b0 packed pairs
        const int idx = gid - 11520;
        const int which = idx / 320, r = idx % 320;
        const int ch = r >> 5, j = r & 31;
        const float* src;
        if (which == 0) src = (ch < NRC) ? (W0_r + ch * HD) : (W0_c + (ch - NRC) * HD);
        else            src = (ch < NRC) ? (b0_r + ch * HD) : (b0_c + (ch - NRC) * HD);
        const uint32_t v = pkh(src[2 * j], src[2 * j + 1]);
        if (which == 0) W0PKD[r] = v; else B0PKD[r] = v;
    }
}

// ---------------------------------------------------------------------------
// main: block = 5 waves x 64 tokens; wave wv handles channels wv and wv+5.
// ALL global IO is cooperative full-line float4 through LDS stage buffers.
// LDS (uint32 words): [0,10240) h-tiles (wave wv at wv*2048, rotated 16B blocks)
//                     [10240,11280) z-stage  [16 ch][65] f32 transposed
//                     [11280,12320) out-stage[16 ch][65] f32 transposed
// 49280 B -> 3 blocks/CU (15 waves/CU). Two __syncthreads total.
// ---------------------------------------------------------------------------
#define ZST 10240
#define OST 11280

__global__ __launch_bounds__(320, 4) void koop_kernel(
    const float* __restrict__ z,
    const float* __restrict__ bm_r, const float* __restrict__ bl_r,
    const float* __restrict__ bm_c, const float* __restrict__ bl_c,
    float* __restrict__ out)
{
    __shared__ uint32_t smem[12320];
    float* smf = (float*)smem;

    const int tid  = threadIdx.x;
    const int lane = tid & 63;
    const int wv   = tid >> 6;        // 0..4
    const int t0   = blockIdx.x * 64; // this block's 64 tokens

    const int l15 = lane & 15;
    const int g   = lane >> 4;
    const int hbase = wv * 2048;

    // ---------------- coop z stage: 4 KB, fully coalesced ----------------
    if (tid < 256) {
        float4 v = ((const float4*)z)[t0 * 4 + tid];
        const int tok = tid >> 2, c0 = (tid & 3) * 4;
        smf[ZST + (c0 + 0) * 65 + tok] = v.x;
        smf[ZST + (c0 + 1) * 65 + tok] = v.y;
        smf[ZST + (c0 + 2) * 65 + tok] = v.z;
        smf[ZST + (c0 + 3) * 65 + tok] = v.w;
    }
    __syncthreads();

    // ---------------- extract channel inputs (lane = token), conflict-free ----------------
    const bool realA = (wv < 4);
    float xinA = 0.f, z1A = 0.f, z2A = 0.f, svA;
    if (realA) {
        xinA = smf[ZST + wv * 65 + lane];
        svA = xinA;
    } else {                                    // wave4, ci=0 -> ch4 = complex pc 0
        z1A = smf[ZST + 4 * 65 + lane];
        z2A = smf[ZST + 5 * 65 + lane];
        svA = z1A * z1A + z2A * z2A;
    }
    const float z1B = smf[ZST + (6 + 2 * wv) * 65 + lane];   // ci=1 -> ch wv+5, pc wv+1
    const float z2B = smf[ZST + (7 + 2 * wv) * 65 + lane];
    const float svB = z1B * z1B + z2B * z2B;

    // ================= per-channel loop =================
    #pragma unroll
    for (int ci = 0; ci < 2; ++ci) {
        const int ch = ci * 5 + wv;
        const bool isReal = (ci == 0) && realA;
        const int  pc     = ch - NRC;
        const float sval = ci ? svB : svA;
        const float z1 = ci ? z1B : z1A;
        const float z2 = ci ? z2B : z2A;

        // ---------------- stage 1: h0 = relu(s*W0 + b0), packed f16, lane = token ----------------
        {
            const half2v sv = u2h(pkh(sval, sval));
            const uint32_t* w0p = &W0PKD[ch * 32];
            const uint32_t* b0p = &B0PKD[ch * 32];
            #pragma unroll
            for (int blk = 0; blk < 8; ++blk) {
                uint32_t q[4];
                #pragma unroll
                for (int j = 0; j < 4; ++j) {
                    half2v h = hfma(sv, u2h(w0p[blk * 4 + j]), u2h(b0p[blk * 4 + j]));
                    q[j] = h2u(hmax0(h));
                }
                const int woff = hbase + lane * 32 + (((blk + lane) & 7) << 2);
                uint4 qq = { q[0], q[1], q[2], q[3] };
                *(uint4*)&smem[woff] = qq;
            }
        }

        // ---------------- two hidden layers via MFMA ----------------
        // D[nH][tok]; D col = token (lane&15), D row = nH = 16*m + 4*g + reg.
        for (int l = 0; l < 2; ++l) {
            const uint32_t* wml = &WMPK[(ch * 2 + l) * 2048];
            half8 A[4][2];
            #pragma unroll
            for (int kt = 0; kt < 2; ++kt)
                #pragma unroll
                for (int m = 0; m < 4; ++m)
                    A[m][kt] = *(const half8*)&wml[(kt * 256 + m * 64 + lane) * 4];

            const float* bm = isReal ? (bm_r + (l * NRC + ch) * HD)
                                     : (bm_c + (l * NCC + pc) * HD);
            f32x4 bv[4];
            #pragma unroll
            for (int m = 0; m < 4; ++m)
                bv[m] = *(const f32x4*)(bm + m * 16 + g * 4);

            #pragma unroll
            for (int th = 0; th < 2; ++th) {
                f32x4 acc[4][2];
                #pragma unroll
                for (int m = 0; m < 4; ++m)
                    #pragma unroll
                    for (int u = 0; u < 2; ++u)
                        acc[m][u] = bv[m];                // bias folded into C

                #pragma unroll
                for (int u = 0; u < 2; ++u) {
                    const int tt = th * 2 + u;
                    #pragma unroll
                    for (int kt = 0; kt < 2; ++kt) {
                        const int row = tt * 16 + l15;
                        const int blk = kt * 4 + g;
                        half8 Bf = *(const half8*)&smem[hbase + row * 32 + (((blk + row) & 7) << 2)];
                        #pragma unroll
                        for (int m = 0; m < 4; ++m)
                            acc[m][u] = __builtin_amdgcn_mfma_f32_16x16x32_f16(A[m][kt], Bf, acc[m][u], 0, 0, 0);
                    }
                }

                // epilogue: pack f16 + packed relu + write back (half-disjoint rows)
                #pragma unroll
                for (int u = 0; u < 2; ++u) {
                    const int tt = th * 2 + u;
                    const int row = tt * 16 + l15;
                    #pragma unroll
                    for (int m = 0; m < 4; ++m) {
                        f32x4 v = acc[m][u];
                        uint32_t p0 = h2u(hmax0(u2h(pkh(v[0], v[1]))));
                        uint32_t p1 = h2u(hmax0(u2h(pkh(v[2], v[3]))));
                        const int blk  = 2 * m + (g >> 1);
                        const int woff = hbase + row * 32 + (((blk + row) & 7) << 2) + (g & 1) * 2;
                        uint2 q = { p0, p1 };
                        *(uint2*)&smem[woff] = q;
                    }
                }
            }
        }

        // ---------------- final layer: out_raw[o][tok] via MFMA (bias in C-init) ----------------
        half8 Af[2];
        #pragma unroll
        for (int kt = 0; kt < 2; ++kt)
            Af[kt] = *(const half8*)&WLPK[(ch * 128 + kt * 64 + lane) * 4];

        const float* bl = isReal ? (bl_r + ch) : (bl_c + pc * 2);
        f32x4 cf0 = (f32x4){0.f, 0.f, 0.f, 0.f};
        if (g == 0) { cf0[0] = bl[0]; if (!isReal) cf0[1] = bl[1]; }
        f32x4 accf[4];
        #pragma unroll
        for (int tt = 0; tt < 4; ++tt) accf[tt] = cf0;
        #pragma unroll
        for (int tt = 0; tt < 4; ++tt) {
            #pragma unroll
            for (int kt = 0; kt < 2; ++kt) {
                const int row = tt * 16 + l15;
                const int blk = kt * 4 + g;
                half8 Bf = *(const half8*)&smem[hbase + row * 32 + (((blk + row) & 7) << 2)];
                accf[tt] = __builtin_amdgcn_mfma_f32_16x16x32_f16(Af[kt], Bf, accf[tt], 0, 0, 0);
            }
        }

        // ---------------- route to lane = token (own h words), then out-stage ----------------
        if (g == 0) {
            #pragma unroll
            for (int tt = 0; tt < 4; ++tt) {
                const int tok = tt * 16 + l15;
                if (isReal) {
                    smf[hbase + tok * 2] = accf[tt][0];
                } else {
                    float2 mo = { accf[tt][0], accf[tt][1] };
                    *(float2*)&smf[hbase + tok * 2] = mo;
                }
            }
        }
        __asm__ volatile("s_waitcnt lgkmcnt(0)" ::: "memory");
        __builtin_amdgcn_sched_barrier(0);

        if (isReal) {
            float lam = smf[hbase + lane * 2];
            smf[OST + ch * 65 + lane] = (ci ? 0.f : xinA) * lam;   // ch = real index
        } else {
            float2 mo = *(const float2*)&smf[hbase + lane * 2];
            float ex = __expf(mo.x);
            float mc = ex * __cosf(mo.y);
            float ms = ex * __sinf(mo.y);
            float o1 =  z1 * mc + z2 * ms;
            float o2 =  z2 * mc - z1 * ms;
            smf[OST + (4 + 2 * pc) * 65 + lane] = o1;
            smf[OST + (5 + 2 * pc) * 65 + lane] = o2;
        }
        // route reads must complete before next channel's stage-1 overwrites h words
        __asm__ volatile("s_waitcnt lgkmcnt(0)" ::: "memory");
        __builtin_amdgcn_sched_barrier(0);
    }
    __syncthreads();

    // ---------------- coop out store: 4 KB, fully coalesced full lines ----------------
    if (tid < 256) {
        const int tok = tid >> 2, c0 = (tid & 3) * 4;
        float4 v;
        v.x = smf[OST + (c0 + 0) * 65 + tok];
        v.y = smf[OST + (c0 + 1) * 65 + tok];
        v.z = smf[OST + (c0 + 2) * 65 + tok];
        v.w = smf[OST + (c0 + 3) * 65 + tok];
        ((float4*)out)[t0 * 4 + tid] = v;
    }
}

extern "C" void kernel_launch(void* const* d_in, const int* in_sizes, int n_in,
                              void* d_out, int out_size, void* d_ws, size_t ws_size,
                              hipStream_t stream) {
    (void)in_sizes; (void)n_in; (void)d_ws; (void)ws_size; (void)out_size;
    const float* z    = (const float*)d_in[0];
    const float* W0_r = (const float*)d_in[1];
    const float* b0_r = (const float*)d_in[2];
    const float* Wm_r = (const float*)d_in[3];
    const float* bm_r = (const float*)d_in[4];
    const float* Wl_r = (const float*)d_in[5];
    const float* bl_r = (const float*)d_in[6];
    const float* W0_c = (const float*)d_in[7];
    const float* b0_c = (const float*)d_in[8];
    const float* Wm_c = (const float*)d_in[9];
    const float* bm_c = (const float*)d_in[10];
    const float* Wl_c = (const float*)d_in[11];
    const float* bl_c = (const float*)d_in[12];
    float* outp = (float*)d_out;

    prep_kernel<<<48, 256, 0, stream>>>(Wm_r, Wm_c, Wl_r, Wl_c, W0_r, W0_c, b0_r, b0_c);
    koop_kernel<<<1024, 320, 0, stream>>>(z, bm_r, bl_r, bm_c, bl_c, outp);
}

// Round 9
// 36.176 us; speedup vs baseline: 2.4319x; 1.2187x over previous
//
#include <hip/hip_runtime.h>
#include <cstdint>

#define NRC 4          // real channels
#define NCC 6          // complex channels
#define HD 64
#define CW 16          // z/out row width (floats)

typedef _Float16 half8  __attribute__((ext_vector_type(8)));
typedef _Float16 half2v __attribute__((ext_vector_type(2)));
typedef float    f32x4  __attribute__((ext_vector_type(4)));

// Block-invariant pre-packed weights (rewritten every call by prep_kernel).
// WMPK frag id f = kt*256 + m*64 + lane  -> lane-contiguous 16B = coalesced loads.
__device__ uint32_t WMPK[40960];   // [ch 10][l 2][frag 512] x half8 (4 u32)
__device__ uint32_t WLPK[5120];    // [ch 10][frag 128 = kt*64+lane] x half8
__device__ uint32_t W0PKD[320];    // [ch 10][32] packed f16 pairs of W0
__device__ uint32_t B0PKD[320];    // [ch 10][32] packed f16 pairs of b0

__device__ __forceinline__ uint32_t pkh(float a, float b) {
    auto h = __builtin_amdgcn_cvt_pkrtz(a, b);   // __fp16 ext_vector(2), 4 bytes
    return __builtin_bit_cast(uint32_t, h);
}
__device__ __forceinline__ half2v u2h(uint32_t u) { return __builtin_bit_cast(half2v, u); }
__device__ __forceinline__ uint32_t h2u(half2v h) { return __builtin_bit_cast(uint32_t, h); }

__device__ __forceinline__ half2v hmax0(half2v h) {
#if __has_builtin(__builtin_elementwise_max)
    half2v z = {};
    return __builtin_elementwise_max(h, z);      // v_pk_max_f16
#else
    half2v r;
    r[0] = h[0] > (_Float16)0 ? h[0] : (_Float16)0;
    r[1] = h[1] > (_Float16)0 ? h[1] : (_Float16)0;
    return r;
#endif
}
__device__ __forceinline__ half2v hfma(half2v a, half2v b, half2v c) {
#if __has_builtin(__builtin_elementwise_fma)
    return __builtin_elementwise_fma(a, b, c);   // v_pk_fma_f16
#else
    return a * b + c;
#endif
}

// ---------------------------------------------------------------------------
// prep: pack weights into MFMA-fragment order, lane-coalesced
// ---------------------------------------------------------------------------
__global__ void prep_kernel(const float* __restrict__ Wm_r, const float* __restrict__ Wm_c,
                            const float* __restrict__ Wl_r, const float* __restrict__ Wl_c,
                            const float* __restrict__ W0_r, const float* __restrict__ W0_c,
                            const float* __restrict__ b0_r, const float* __restrict__ b0_c)
{
    const int gid = blockIdx.x * 256 + threadIdx.x;
    if (gid < 10240) {                          // hidden-layer fragments
        const int ch = gid >> 10, rem = gid & 1023;
        const int l = rem >> 9, f = rem & 511;
        const int kt = f >> 8, m = (f >> 6) & 3, lane = f & 63;
        const int g = (lane >> 4) & 3, l15 = lane & 15;
        const int n = m * 16 + l15;
        const int k0 = (kt * 4 + g) * 8;
        const float* W = (ch < NRC) ? (Wm_r + (l * NRC + ch) * HD * HD)
                                    : (Wm_c + (l * NCC + (ch - NRC)) * HD * HD);
        const float* s = W + k0 * HD + n;                // W[k][n], stride HD per k
        uint4 q = { pkh(s[0],      s[HD]),
                    pkh(s[2*HD],   s[3*HD]),
                    pkh(s[4*HD],   s[5*HD]),
                    pkh(s[6*HD],   s[7*HD]) };
        *(uint4*)&WMPK[gid * 4] = q;
    } else if (gid < 11520) {                   // final-layer fragments
        const int idx = gid - 10240;
        const int ch = idx >> 7, f = idx & 127;
        const int kt = f >> 6, lane = f & 63;
        const int g = (lane >> 4) & 3, l15 = lane & 15;
        const int No = (ch < NRC) ? 1 : 2;
        const float* Wl = (ch < NRC) ? (Wl_r + ch * HD) : (Wl_c + (ch - NRC) * HD * 2);
        float v[8];
        #pragma unroll
        for (int e = 0; e < 8; ++e)
            v[e] = (l15 < No) ? Wl[((kt * 4 + g) * 8 + e) * No + l15] : 0.f;
        uint4 q = { pkh(v[0], v[1]), pkh(v[2], v[3]), pkh(v[4], v[5]), pkh(v[6], v[7]) };
        *(uint4*)&WLPK[idx * 4] = q;
    } else if (gid < 12160) {                   // W0 / b0 packed pairs
        const int idx = gid - 11520;
        const int which = idx / 320, r = idx % 320;
        const int ch = r >> 5, j = r & 31;
        const float* src;
        if (which == 0) src = (ch < NRC) ? (W0_r + ch * HD) : (W0_c + (ch - NRC) * HD);
        else            src = (ch < NRC) ? (b0_r + ch * HD) : (b0_c + (ch - NRC) * HD);
        const uint32_t v = pkh(src[2 * j], src[2 * j + 1]);
        if (which == 0) W0PKD[r] = v; else B0PKD[r] = v;
    }
}

// ---------------------------------------------------------------------------
// main: one channel per block, 4 waves x 64 tokens (tile = 256 tokens).
// bid -> (tile, ch) mapping pins ALL 10 channel-blocks of a tile to the SAME
// XCD (bid%8 == tile%8) and makes them temporally adjacent -> out lines (one
// 64B line per token) merge in that XCD's L2; z lines fetched once, read 10x.
// LDS = h tiles only: 4 waves x 2048 words = 32768 B -> 5 blocks/CU.
// No __syncthreads anywhere.
// ---------------------------------------------------------------------------
__global__ __launch_bounds__(256, 5) void koop_kernel(
    const float* __restrict__ z,
    const float* __restrict__ bm_r, const float* __restrict__ bl_r,
    const float* __restrict__ bm_c, const float* __restrict__ bl_c,
    float* __restrict__ out)
{
    __shared__ uint32_t smem[8192];
    float* smf = (float*)smem;

    const int tid  = threadIdx.x;
    const int lane = tid & 63;
    const int wv   = tid >> 6;
    const int bid  = blockIdx.x;

    // XCD-pinned, tile-adjacent decomposition (bijective over 2560):
    const int x    = bid & 7;
    const int j    = bid >> 3;
    const int ch   = j % 10;
    const int tile = x + 8 * (j / 10);
    const int t0   = tile * 256;

    const bool isReal = (ch < NRC);
    const int  pc     = ch - NRC;

    const int l15 = lane & 15;
    const int g   = lane >> 4;
    const int hbase = wv * 2048;

    // ---------------- per-lane token input ----------------
    const int t = t0 + wv * 64 + lane;
    float xin = 0.f, z1 = 0.f, z2 = 0.f, sval;
    if (isReal) {
        xin = z[t * CW + ch];
        sval = xin;
    } else {
        float2 zz = *(const float2*)(z + t * CW + NRC + 2 * pc);
        z1 = zz.x; z2 = zz.y;
        sval = z1 * z1 + z2 * z2;
    }

    // ---------------- stage 1: h0 = relu(s*W0 + b0), packed f16, lane = token ----------------
    {
        const half2v sv = u2h(pkh(sval, sval));
        const uint32_t* w0p = &W0PKD[ch * 32];
        const uint32_t* b0p = &B0PKD[ch * 32];
        #pragma unroll
        for (int blk = 0; blk < 8; ++blk) {
            uint32_t q[4];
            #pragma unroll
            for (int jj = 0; jj < 4; ++jj) {
                half2v h = hfma(sv, u2h(w0p[blk * 4 + jj]), u2h(b0p[blk * 4 + jj]));
                q[jj] = h2u(hmax0(h));
            }
            const int woff = hbase + lane * 32 + (((blk + lane) & 7) << 2);
            uint4 qq = { q[0], q[1], q[2], q[3] };
            *(uint4*)&smem[woff] = qq;
        }
    }

    // ---------------- two hidden layers via MFMA ----------------
    // D[nH][tok]; D col = token (lane&15), D row = nH = 16*m + 4*g + reg.
    for (int l = 0; l < 2; ++l) {
        const uint32_t* wml = &WMPK[(ch * 2 + l) * 2048];
        half8 A[4][2];
        #pragma unroll
        for (int kt = 0; kt < 2; ++kt)
            #pragma unroll
            for (int m = 0; m < 4; ++m)
                A[m][kt] = *(const half8*)&wml[(kt * 256 + m * 64 + lane) * 4];

        const float* bm = isReal ? (bm_r + (l * NRC + ch) * HD)
                                 : (bm_c + (l * NCC + pc) * HD);
        f32x4 bv[4];
        #pragma unroll
        for (int m = 0; m < 4; ++m)
            bv[m] = *(const f32x4*)(bm + m * 16 + g * 4);

        #pragma unroll
        for (int th = 0; th < 2; ++th) {
            f32x4 acc[4][2];
            #pragma unroll
            for (int m = 0; m < 4; ++m)
                #pragma unroll
                for (int u = 0; u < 2; ++u)
                    acc[m][u] = bv[m];                    // bias folded into C

            #pragma unroll
            for (int u = 0; u < 2; ++u) {
                const int tt = th * 2 + u;
                #pragma unroll
                for (int kt = 0; kt < 2; ++kt) {
                    const int row = tt * 16 + l15;
                    const int blk = kt * 4 + g;
                    half8 Bf = *(const half8*)&smem[hbase + row * 32 + (((blk + row) & 7) << 2)];
                    #pragma unroll
                    for (int m = 0; m < 4; ++m)
                        acc[m][u] = __builtin_amdgcn_mfma_f32_16x16x32_f16(A[m][kt], Bf, acc[m][u], 0, 0, 0);
                }
            }

            // epilogue: pack f16 + packed relu + write back (half-disjoint rows)
            #pragma unroll
            for (int u = 0; u < 2; ++u) {
                const int tt = th * 2 + u;
                const int row = tt * 16 + l15;
                #pragma unroll
                for (int m = 0; m < 4; ++m) {
                    f32x4 v = acc[m][u];
                    uint32_t p0 = h2u(hmax0(u2h(pkh(v[0], v[1]))));
                    uint32_t p1 = h2u(hmax0(u2h(pkh(v[2], v[3]))));
                    const int blk  = 2 * m + (g >> 1);
                    const int woff = hbase + row * 32 + (((blk + row) & 7) << 2) + (g & 1) * 2;
                    uint2 q = { p0, p1 };
                    *(uint2*)&smem[woff] = q;
                }
            }
        }
    }

    // ---------------- final layer: out_raw[o][tok] via MFMA (bias in C-init) ----------------
    half8 Af[2];
    #pragma unroll
    for (int kt = 0; kt < 2; ++kt)
        Af[kt] = *(const half8*)&WLPK[(ch * 128 + kt * 64 + lane) * 4];

    const float* bl = isReal ? (bl_r + ch) : (bl_c + pc * 2);
    f32x4 cf0 = (f32x4){0.f, 0.f, 0.f, 0.f};
    if (g == 0) { cf0[0] = bl[0]; if (!isReal) cf0[1] = bl[1]; }
    f32x4 accf[4];
    #pragma unroll
    for (int tt = 0; tt < 4; ++tt) accf[tt] = cf0;
    #pragma unroll
    for (int tt = 0; tt < 4; ++tt) {
        #pragma unroll
        for (int kt = 0; kt < 2; ++kt) {
            const int row = tt * 16 + l15;
            const int blk = kt * 4 + g;
            half8 Bf = *(const half8*)&smem[hbase + row * 32 + (((blk + row) & 7) << 2)];
            accf[tt] = __builtin_amdgcn_mfma_f32_16x16x32_f16(Af[kt], Bf, accf[tt], 0, 0, 0);
        }
    }

    // ---------------- route results to lane = token (wave-local, reuse own h words) ----------------
    const int obase = hbase;          // words [hbase, hbase+128): 64 tok x 2 f32
    if (g == 0) {
        #pragma unroll
        for (int tt = 0; tt < 4; ++tt) {
            const int tok = tt * 16 + l15;
            if (isReal) {
                smf[obase + tok * 2] = accf[tt][0];
            } else {
                float2 mo = { accf[tt][0], accf[tt][1] };
                *(float2*)&smf[obase + tok * 2] = mo;
            }
        }
    }
    __asm__ volatile("s_waitcnt lgkmcnt(0)" ::: "memory");
    __builtin_amdgcn_sched_barrier(0);

    if (isReal) {
        float lam = smf[obase + lane * 2];
        out[t * CW + ch] = xin * lam;
    } else {
        float2 mo = *(const float2*)&smf[obase + lane * 2];
        float ex = __expf(mo.x);
        float mc = ex * __cosf(mo.y);
        float ms = ex * __sinf(mo.y);
        float o1 =  z1 * mc + z2 * ms;
        float o2 =  z2 * mc - z1 * ms;
        *(float2*)(out + t * CW + NRC + 2 * pc) = make_float2(o1, o2);
    }
}

extern "C" void kernel_launch(void* const* d_in, const int* in_sizes, int n_in,
                              void* d_out, int out_size, void* d_ws, size_t ws_size,
                              hipStream_t stream) {
    (void)in_sizes; (void)n_in; (void)d_ws; (void)ws_size; (void)out_size;
    const float* z    = (const float*)d_in[0];
    const float* W0_r = (const float*)d_in[1];
    const float* b0_r = (const float*)d_in[2];
    const float* Wm_r = (const float*)d_in[3];
    const float* bm_r = (const float*)d_in[4];
    const float* Wl_r = (const float*)d_in[5];
    const float* bl_r = (const float*)d_in[6];
    const float* W0_c = (const float*)d_in[7];
    const float* b0_c = (const float*)d_in[8];
    const float* Wm_c = (const float*)d_in[9];
    const float* bm_c = (const float*)d_in[10];
    const float* Wl_c = (const float*)d_in[11];
    const float* bl_c = (const float*)d_in[12];
    float* outp = (float*)d_out;

    prep_kernel<<<48, 256, 0, stream>>>(Wm_r, Wm_c, Wl_r, Wl_c, W0_r, W0_c, b0_r, b0_c);
    koop_kernel<<<2560, 256, 0, stream>>>(z, bm_r, bl_r, bm_c, bl_c, outp);
}

// Round 10
// 28.732 us; speedup vs baseline: 3.0620x; 1.2591x over previous
//
#include <hip/hip_runtime.h>
#include <cstdint>

#define NRC 4          // real channels
#define NCC 6          // complex channels
#define HD 64
#define CW 16          // z/out row width (floats)

typedef _Float16 half8  __attribute__((ext_vector_type(8)));
typedef _Float16 half2v __attribute__((ext_vector_type(2)));
typedef float    f32x4  __attribute__((ext_vector_type(4)));

__device__ __forceinline__ uint32_t pkh(float a, float b) {
    auto h = __builtin_amdgcn_cvt_pkrtz(a, b);   // __fp16 ext_vector(2), 4 bytes
    return __builtin_bit_cast(uint32_t, h);
}
__device__ __forceinline__ half2v u2h(uint32_t u) { return __builtin_bit_cast(half2v, u); }
__device__ __forceinline__ uint32_t h2u(half2v h) { return __builtin_bit_cast(uint32_t, h); }
__device__ __forceinline__ half2v hmax0(half2v h) {
#if __has_builtin(__builtin_elementwise_max)
    half2v zz = {};
    return __builtin_elementwise_max(h, zz);     // v_pk_max_f16
#else
    half2v r;
    r[0] = h[0] > (_Float16)0 ? h[0] : (_Float16)0;
    r[1] = h[1] > (_Float16)0 ? h[1] : (_Float16)0;
    return r;
#endif
}

// LDS word map (uint32 units), 10240 words = 40960 B -> exactly 4 blocks/CU:
//   [0,    8192)  : h tiles, wave wv at [wv*2048, +2048)  (64 tokens x 32 words, rotated 16B blocks)
//                   layer-1 W^T STAGED TEMPORARILY at [0,2048) (wave0's h area),
//                   read into registers by all waves before wave0 overwrites it.
//   [8192, 10240) : layer-2 W^T f16, persistent (64 rows x 32 words, rotated)
//   route buffer  : reuses own wave's h words [hbase, hbase+128) (dead after final B-reads)
__global__ __launch_bounds__(256, 4) void koop_kernel(
    const float* __restrict__ z,
    const float* __restrict__ W0_r, const float* __restrict__ b0_r,
    const float* __restrict__ Wm_r, const float* __restrict__ bm_r,
    const float* __restrict__ Wl_r, const float* __restrict__ bl_r,
    const float* __restrict__ W0_c, const float* __restrict__ b0_c,
    const float* __restrict__ Wm_c, const float* __restrict__ bm_c,
    const float* __restrict__ Wl_c, const float* __restrict__ bl_c,
    float* __restrict__ out)
{
    __shared__ uint32_t smem[10240];

    const int tid  = threadIdx.x;
    const int lane = tid & 63;
    const int wv   = tid >> 6;
    const int bid  = blockIdx.x;
    const int ch   = bid >> 8;        // consecutive blocks share a channel (L2 weight locality)
    const int tile = bid & 255;
    const int t0   = tile * 256;

    const bool isReal = (ch < NRC);
    const int  pc     = ch - NRC;
    const int  No     = isReal ? 1 : 2;

    const float* W0 = isReal ? (W0_r + ch * HD) : (W0_c + pc * HD);
    const float* b0 = isReal ? (b0_r + ch * HD) : (b0_c + pc * HD);
    const float* Wl = isReal ? (Wl_r + ch * HD) : (Wl_c + pc * HD * 2);
    const float* bl = isReal ? (bl_r + ch)      : (bl_c + pc * 2);

    const int l15 = lane & 15;
    const int g   = lane >> 4;

    // ---------------- z load FIRST: HBM/L2 latency overlaps weight staging ----------------
    const int t = t0 + wv * 64 + lane;
    float xin = 0.f, z1 = 0.f, z2 = 0.f, sval;
    if (isReal) {
        xin = z[t * CW + ch];
        sval = xin;
    } else {
        float2 zz = *(const float2*)(z + t * CW + NRC + 2 * pc);
        z1 = zz.x; z2 = zz.y;
        sval = z1 * z1 + z2 * z2;
    }

    // ---------------- stage W^T (f16): L1 -> [0,2048) temp, L2 -> [8192,10240) ----------------
    {
        const int nH = tid & 63;
        const int bb = (tid >> 6) * 2;
        for (int l = 0; l < 2; ++l) {
            const float* Wm = isReal ? (Wm_r + (l * NRC + ch) * HD * HD)
                                     : (Wm_c + (l * NCC + pc) * HD * HD);
            const int base = l ? 8192 : 0;
            #pragma unroll
            for (int r = 0; r < 2; ++r) {
                const int blk = bb + r;                    // k-block (8 k values)
                const float* src = Wm + blk * 8 * HD + nH; // W[k][nH], stride HD per k
                float v0 = src[0],    v1 = src[HD],   v2 = src[2*HD], v3 = src[3*HD];
                float v4 = src[4*HD], v5 = src[5*HD], v6 = src[6*HD], v7 = src[7*HD];
                const int woff = base + nH * 32 + (((blk + nH) & 7) << 2);
                uint4 q = { pkh(v0, v1), pkh(v2, v3), pkh(v4, v5), pkh(v6, v7) };
                *(uint4*)&smem[woff] = q;
            }
        }
    }
    __syncthreads();

    // ---------------- pre-read BOTH layers' A fragments into registers ----------------
    half8 A1[4][2], A2[4][2];
    #pragma unroll
    for (int m = 0; m < 4; ++m) {
        #pragma unroll
        for (int kt = 0; kt < 2; ++kt) {
            const int row = m * 16 + l15;
            const int blk = kt * 4 + g;
            const int rot = (((blk + row) & 7) << 2);
            A1[m][kt] = *(const half8*)&smem[row * 32 + rot];
            A2[m][kt] = *(const half8*)&smem[8192 + row * 32 + rot];
        }
    }
    __syncthreads();   // all A1 reads done before wave0 overwrites [0,2048)

    // ---------------- stage 1: h0 = relu(s*W0 + b0), lane = token ----------------
    const int hbase = wv * 2048;
    {
        #pragma unroll
        for (int blk = 0; blk < 8; ++blk) {
            uint32_t q0, q1, q2, q3;
            {
                const int n = blk * 8;
                float a0 = fmaxf(fmaf(sval, W0[n+0], b0[n+0]), 0.f);
                float a1 = fmaxf(fmaf(sval, W0[n+1], b0[n+1]), 0.f);
                float a2 = fmaxf(fmaf(sval, W0[n+2], b0[n+2]), 0.f);
                float a3 = fmaxf(fmaf(sval, W0[n+3], b0[n+3]), 0.f);
                float a4 = fmaxf(fmaf(sval, W0[n+4], b0[n+4]), 0.f);
                float a5 = fmaxf(fmaf(sval, W0[n+5], b0[n+5]), 0.f);
                float a6 = fmaxf(fmaf(sval, W0[n+6], b0[n+6]), 0.f);
                float a7 = fmaxf(fmaf(sval, W0[n+7], b0[n+7]), 0.f);
                q0 = pkh(a0, a1); q1 = pkh(a2, a3); q2 = pkh(a4, a5); q3 = pkh(a6, a7);
            }
            const int woff = hbase + lane * 32 + (((blk + lane) & 7) << 2);
            uint4 q = { q0, q1, q2, q3 };
            *(uint4*)&smem[woff] = q;
        }
    }

    // ---------------- two hidden layers via MFMA (A in registers, no mid-layer LDS A reads) ----------------
    // D[nH][tok]; D col = token (lane&15), D row = nH = 16*m + 4*g + reg.
    #pragma unroll
    for (int l = 0; l < 2; ++l) {
        const half8 (*Ap)[2] = l ? A2 : A1;
        const float* bm = isReal ? (bm_r + (l * NRC + ch) * HD)
                                 : (bm_c + (l * NCC + pc) * HD);
        f32x4 bv[4];
        #pragma unroll
        for (int m = 0; m < 4; ++m)
            bv[m] = *(const f32x4*)(bm + m * 16 + g * 4);

        #pragma unroll
        for (int th = 0; th < 2; ++th) {
            f32x4 acc[4][2];
            #pragma unroll
            for (int m = 0; m < 4; ++m)
                #pragma unroll
                for (int u = 0; u < 2; ++u)
                    acc[m][u] = bv[m];                    // bias folded into C

            #pragma unroll
            for (int u = 0; u < 2; ++u) {
                const int tt = th * 2 + u;
                #pragma unroll
                for (int kt = 0; kt < 2; ++kt) {
                    const int row = tt * 16 + l15;
                    const int blk = kt * 4 + g;
                    half8 Bf = *(const half8*)&smem[hbase + row * 32 + (((blk + row) & 7) << 2)];
                    #pragma unroll
                    for (int m = 0; m < 4; ++m)
                        acc[m][u] = __builtin_amdgcn_mfma_f32_16x16x32_f16(Ap[m][kt], Bf, acc[m][u], 0, 0, 0);
                }
            }

            // epilogue: pack f16 (RTZ) + packed relu + write back (half-disjoint rows)
            #pragma unroll
            for (int u = 0; u < 2; ++u) {
                const int tt = th * 2 + u;
                const int row = tt * 16 + l15;
                #pragma unroll
                for (int m = 0; m < 4; ++m) {
                    f32x4 v = acc[m][u];
                    uint32_t p0 = h2u(hmax0(u2h(pkh(v[0], v[1]))));
                    uint32_t p1 = h2u(hmax0(u2h(pkh(v[2], v[3]))));
                    const int blk  = 2 * m + (g >> 1);
                    const int woff = hbase + row * 32 + (((blk + row) & 7) << 2) + (g & 1) * 2;
                    uint2 q = { p0, p1 };
                    *(uint2*)&smem[woff] = q;
                }
            }
        }
    }

    // ---------------- final layer: out_raw[o][tok] via MFMA (o rows, bias in C-init) ----------------
    half8 Af[2];
    #pragma unroll
    for (int kt = 0; kt < 2; ++kt) {
        half8 a;
        #pragma unroll
        for (int e = 0; e < 8; ++e) {
            const int k = kt * 32 + g * 8 + e;
            float w = (l15 < No) ? Wl[k * No + l15] : 0.f;
            a[e] = (_Float16)w;
        }
        Af[kt] = a;
    }
    f32x4 cf0 = (f32x4){0.f, 0.f, 0.f, 0.f};
    if (g == 0) { cf0[0] = bl[0]; if (!isReal) cf0[1] = bl[1]; }
    f32x4 accf[4];
    #pragma unroll
    for (int tt = 0; tt < 4; ++tt) accf[tt] = cf0;
    #pragma unroll
    for (int tt = 0; tt < 4; ++tt) {
        #pragma unroll
        for (int kt = 0; kt < 2; ++kt) {
            const int row = tt * 16 + l15;
            const int blk = kt * 4 + g;
            half8 Bf = *(const half8*)&smem[hbase + row * 32 + (((blk + row) & 7) << 2)];
            accf[tt] = __builtin_amdgcn_mfma_f32_16x16x32_f16(Af[kt], Bf, accf[tt], 0, 0, 0);
        }
    }

    // ---------------- route results to lane = token (wave-local, reuse own h words) ----------------
    float* smf = (float*)smem;
    const int obase = hbase;            // words [hbase, hbase+128): 64 tok x 2 f32
    if (g == 0) {
        #pragma unroll
        for (int tt = 0; tt < 4; ++tt) {
            const int tok = tt * 16 + l15;
            if (isReal) {
                smf[obase + tok * 2] = accf[tt][0];
            } else {
                float2 mo = { accf[tt][0], accf[tt][1] };
                *(float2*)&smf[obase + tok * 2] = mo;
            }
        }
    }
    __asm__ volatile("s_waitcnt lgkmcnt(0)" ::: "memory");
    __builtin_amdgcn_sched_barrier(0);

    if (isReal) {
        float lam = smf[obase + lane * 2];
        out[t * CW + ch] = xin * lam;
    } else {
        float2 mo = *(const float2*)&smf[obase + lane * 2];
        float ex = __expf(mo.x);
        float mc = ex * __cosf(mo.y);
        float ms = ex * __sinf(mo.y);
        float o1 =  z1 * mc + z2 * ms;
        float o2 =  z2 * mc - z1 * ms;
        *(float2*)(out + t * CW + NRC + 2 * pc) = make_float2(o1, o2);
    }
}

extern "C" void kernel_launch(void* const* d_in, const int* in_sizes, int n_in,
                              void* d_out, int out_size, void* d_ws, size_t ws_size,
                              hipStream_t stream) {
    (void)in_sizes; (void)n_in; (void)d_ws; (void)ws_size; (void)out_size;
    const float* z    = (const float*)d_in[0];
    const float* W0_r = (const float*)d_in[1];
    const float* b0_r = (const float*)d_in[2];
    const float* Wm_r = (const float*)d_in[3];
    const float* bm_r = (const float*)d_in[4];
    const float* Wl_r = (const float*)d_in[5];
    const float* bl_r = (const float*)d_in[6];
    const float* W0_c = (const float*)d_in[7];
    const float* b0_c = (const float*)d_in[8];
    const float* Wm_c = (const float*)d_in[9];
    const float* bm_c = (const float*)d_in[10];
    const float* Wl_c = (const float*)d_in[11];
    const float* bl_c = (const float*)d_in[12];
    float* outp = (float*)d_out;

    dim3 grid(2560), block(256);
    koop_kernel<<<grid, block, 0, stream>>>(z, W0_r, b0_r, Wm_r, bm_r, Wl_r, bl_r,
                                            W0_c, b0_c, Wm_c, bm_c, Wl_c, bl_c, outp);
}